// Round 3
// baseline (37.884 us; speedup 1.0000x reference)
//
#include <hip/hip_runtime.h>
#include <hip/hip_bf16.h>

// ExtraMSAEmbedding: out[p, o] = W[o, msa[p]] + hd[p]*W[o,23] + dv[p]*W[o,24] + b[o]
// p = flattened (seq, res) position, 2048*384 = 786432 positions, o in [0,64).
// Write-bound: 201 MB f32 output (fits L3) vs ~9.4 MB input reads.
// Fill-kernel ceiling ~7.0 TB/s at 10.5% occupancy -> store drain needs few waves;
// this version is straight-line (no grid-stride loop), UNROLL=8, normal stores.

#define C_IN   25
#define C_OUT  64
#define TPAD   68   // row stride in floats: 272 B, 16B-aligned, breaks 256B bank period
#define UNROLL 8    // positions per thread; block covers 128 positions

typedef float v4f __attribute__((ext_vector_type(4)));

__global__ __launch_bounds__(256) void extra_msa_emb_kernel(
    const int* __restrict__ msa,
    const float* __restrict__ hd,
    const float* __restrict__ dv,
    const float* __restrict__ W,   // [64, 25] row-major
    const float* __restrict__ b,   // [64]
    float* __restrict__ out) {     // [npos, 64]
    // Fused table, transposed + padded: T[c][o] = W[o*25+c] (+ b[o] when c < 23).
    __shared__ float T[C_IN][TPAD];
    const int tid = threadIdx.x;
    for (int idx = tid; idx < C_IN * C_OUT; idx += 256) {
        const int c = idx >> 6;      // idx / 64
        const int o = idx & 63;      // idx % 64
        float v = W[o * C_IN + c];
        if (c < 23) v += b[o];
        T[c][o] = v;
    }
    __syncthreads();

    const int group = tid >> 4;   // 16 groups; wave w covers groups 4w..4w+3
    const int lane  = tid & 15;   // 16 threads per position
    const int o     = lane * 4;   // each thread owns 4 consecutive outputs

    // One shot: block covers positions [blockIdx.x*128, +128).
    // Thread handles positions pbase + j*16, j = 0..7.
    const int pbase = blockIdx.x * 128 + group;

    // Issue all 24 input loads up front (max MLP; no loop-carried deps).
    int   cls[UNROLL];
    float h[UNROLL], d[UNROLL];
#pragma unroll
    for (int j = 0; j < UNROLL; ++j) {
        const int p = pbase + j * 16;
        cls[j] = msa[p];
        h[j]   = hd[p];
        d[j]   = dv[p];
    }

    const v4f w23 = *reinterpret_cast<const v4f*>(&T[23][o]);
    const v4f w24 = *reinterpret_cast<const v4f*>(&T[24][o]);

    v4f t[UNROLL];
#pragma unroll
    for (int j = 0; j < UNROLL; ++j)
        t[j] = *reinterpret_cast<const v4f*>(&T[cls[j]][o]);

    // Wave stores: per j, 64 lanes cover 4 consecutive positions = 1 KB contiguous.
    // Normal (cached) stores: output fits in L3, let Infinity Cache absorb.
#pragma unroll
    for (int j = 0; j < UNROLL; ++j) {
        const v4f r = t[j] + h[j] * w23 + d[j] * w24;
        const long long p = (long long)(pbase + j * 16);
        *reinterpret_cast<v4f*>(&out[p * C_OUT + o]) = r;
    }
}

extern "C" void kernel_launch(void* const* d_in, const int* in_sizes, int n_in,
                              void* d_out, int out_size, void* d_ws, size_t ws_size,
                              hipStream_t stream) {
    const int*   msa = (const int*)d_in[0];
    const float* hd  = (const float*)d_in[1];
    const float* dv  = (const float*)d_in[2];
    const float* W   = (const float*)d_in[3];
    const float* b   = (const float*)d_in[4];
    float* out = (float*)d_out;

    const int npos = in_sizes[0];  // 2048 * 384 = 786432, divisible by 128

    const int block = 256;
    const int grid  = npos / 128;  // 6144 blocks, one 128-position chunk each
    extra_msa_emb_kernel<<<grid, block, 0, stream>>>(msa, hd, dv, W, b, out);
}